// Round 13
// baseline (117.821 us; speedup 1.0000x reference)
//
#include <hip/hip_runtime.h>
#include <hip/hip_bf16.h>

// ---- problem constants (match reference) ----
#define BB 2048
#define NN 64
#define DD 64
#define HH 256
#define L_HAND 16
#define L_UNIT 8
#define L_CE 8
#define L_SK 8
#define L_VS 16
#define L_ME 16
#define L_TGT 8
#define STATE_SC 64
#define CE_SC 8
#define SITE_SC 6
#define ME_SC 8
#define ACT_SC 16
#define STATE_IN 662
#define ACT_IN 464

#define SROWS 2      // batch rows per block in state kernel
#define SK 672       // state K padded to 21*32
#define SSTRIDE 676  // fp32 LDS row stride

typedef __attribute__((ext_vector_type(8))) short short8;   // 8 bf16 = 4 VGPRs
typedef __attribute__((ext_vector_type(4))) float f32x4;    // MFMA accum

__device__ __forceinline__ float fast_tanh(float x) {
    float e = __expf(2.0f * x);
    return 1.0f - 2.0f * __builtin_amdgcn_rcpf(e + 1.0f);
}
__device__ __forceinline__ short f2bs(float x) {
    __hip_bfloat16 h = __float2bfloat16(x);
    return *reinterpret_cast<short*>(&h);
}
__device__ __forceinline__ float bs2f(short u) {
    union { unsigned int i; float f; } v;
    v.i = ((unsigned int)(unsigned short)u) << 16;
    return v.f;
}
// async global->LDS 16B per lane: per-lane global src, wave-uniform LDS base
__device__ __forceinline__ void async_copy16(const void* gsrc, void* ldst) {
    __builtin_amdgcn_global_load_lds(
        (const __attribute__((address_space(1))) unsigned int*)gsrc,
        (__attribute__((address_space(3))) unsigned int*)ldst, 16, 0, 0);
}
// sum over each 16-lane row via DPP row_shr adds; lane (l&15)==15 holds the sum
__device__ __forceinline__ float sum16_dpp(float v) {
    int x;
    x = __builtin_amdgcn_update_dpp(0, __float_as_int(v), 0x111, 0xf, 0xf, true);
    v += __int_as_float(x);
    x = __builtin_amdgcn_update_dpp(0, __float_as_int(v), 0x112, 0xf, 0xf, true);
    v += __int_as_float(x);
    x = __builtin_amdgcn_update_dpp(0, __float_as_int(v), 0x114, 0xf, 0xf, true);
    v += __int_as_float(x);
    x = __builtin_amdgcn_update_dpp(0, __float_as_int(v), 0x118, 0xf, 0xf, true);
    v += __int_as_float(x);
    return v;
}

// emb16 row offsets: at(50), src(30), card(400), unit(100), enemy(120), skill(60)
#define RO_AT    0
#define RO_SRC   50
#define RO_CARD  80
#define RO_UNIT  480
#define RO_ENEMY 580
#define RO_SKILL 700
#define EMB_ROWS 760

// pack segment boundaries
#define T0 (480 * 256)            // WaP
#define T1 (T0 + 256 * 256)       // W1bP
#define T2 (T1 + EMB_ROWS * 64)   // emb16
#define T3 (T2 + SK * 256)        // WsP
#define T4 (T3 + 256 * 256)       // W1aP

// ===================== weight + embedding pre-pack kernel =====================
__global__ __launch_bounds__(256) void pack_kernel(
    const float* __restrict__ W_a, const float* __restrict__ W1,
    const float* __restrict__ W_s,
    const float* __restrict__ at_emb, const float* __restrict__ src_emb,
    const float* __restrict__ card_emb, const float* __restrict__ unit_emb,
    const float* __restrict__ enemy_emb, const float* __restrict__ skill_emb,
    ushort* __restrict__ WaP, ushort* __restrict__ W1bP, ushort* __restrict__ emb16,
    ushort* __restrict__ WsP, ushort* __restrict__ W1aP)
{
    const int idx = blockIdx.x * 256 + threadIdx.x;
    if (idx < T0) {
        const int k = idx >> 8, n = idx & 255;
        const float v = (k < ACT_IN) ? W_a[k * HH + n] : 0.f;
        const int pi = (((k >> 5) * 16 + (n >> 4)) * 64 +
                        ((n & 15) + 16 * ((k >> 3) & 3))) * 8 + (k & 7);
        WaP[pi] = (ushort)f2bs(v);
    } else if (idx < T1) {
        const int j = idx - T0;
        const int k = j >> 8, n = j & 255;
        const float v = W1[(256 + k) * HH + n];
        const int pi = (((k >> 5) * 16 + (n >> 4)) * 64 +
                        ((n & 15) + 16 * ((k >> 3) & 3))) * 8 + (k & 7);
        W1bP[pi] = (ushort)f2bs(v);
    } else if (idx < T2) {
        const int j = idx - T1;
        const int row = j >> 6, d = j & 63;
        float v;
        if      (row < RO_SRC)   v = at_emb[row * 64 + d];
        else if (row < RO_CARD)  v = src_emb[(row - RO_SRC) * 64 + d];
        else if (row < RO_UNIT)  v = card_emb[(row - RO_CARD) * 64 + d];
        else if (row < RO_ENEMY) v = unit_emb[(row - RO_UNIT) * 64 + d];
        else if (row < RO_SKILL) v = enemy_emb[(row - RO_ENEMY) * 64 + d];
        else                     v = skill_emb[(row - RO_SKILL) * 64 + d];
        emb16[j] = (ushort)f2bs(v);
    } else if (idx < T3) {
        const int j = idx - T2;
        const int k = j >> 8, n = j & 255;
        const float v = (k < STATE_IN) ? W_s[k * HH + n] : 0.f;
        const int pi = (((k >> 5) * 16 + (n >> 4)) * 64 +
                        ((n & 15) + 16 * ((k >> 3) & 3))) * 8 + (k & 7);
        WsP[pi] = (ushort)f2bs(v);
    } else if (idx < T4) {
        const int j = idx - T3;
        const int k = j >> 8, n = j & 255;
        const float v = W1[k * HH + n];   // first (state) half of W1
        const int pi = (((k >> 5) * 16 + (n >> 4)) * 64 +
                        ((n & 15) + 16 * ((k >> 3) & 3))) * 8 + (k & 7);
        W1aP[pi] = (ushort)f2bs(v);
    }
}

// ===================== state encoding kernel (MFMA, chunk-vectorized builder) ====
__global__ __launch_bounds__(256) void state_mfma_kernel(
    const float* __restrict__ state_scalars,
    const int* __restrict__ mode_id, const int* __restrict__ terrain_id,
    const int* __restrict__ site_type_id,
    const int* __restrict__ hand_ids, const int* __restrict__ hand_mask,
    const int* __restrict__ unit_ids, const int* __restrict__ unit_mask,
    const int* __restrict__ ce_ids, const float* __restrict__ ce_sc, const int* __restrict__ ce_mask,
    const int* __restrict__ skill_ids, const int* __restrict__ skill_mask,
    const int* __restrict__ vs_ids, const float* __restrict__ vs_sc, const int* __restrict__ vs_mask,
    const int* __restrict__ me_ids, const float* __restrict__ me_sc, const int* __restrict__ me_mask,
    const float* __restrict__ mode_emb, const float* __restrict__ ter_emb,
    const float* __restrict__ site_emb, const float* __restrict__ msite_emb,
    const ushort* __restrict__ emb16,
    const ushort* __restrict__ WsP, const float* __restrict__ b_s,
    const ushort* __restrict__ W1aP,
    const float* __restrict__ W_v, const float* __restrict__ b_v,
    float* __restrict__ s_part, float* __restrict__ out_value)
{
    __shared__ float s_in[SROWS * SSTRIDE];   // 5,408 B
    __shared__ ushort sA2[8 * 64 * 8];        // 8,192 B (GEMM2 A, bf16 packed)
    __shared__ float red[4][4];

    const int t = threadIdx.x;
    const int b0 = blockIdx.x * SROWS;
    const int w = t >> 6;
    const int lane = t & 63;
    const ushort* card16  = emb16 + RO_CARD  * 64;
    const ushort* unit16  = emb16 + RO_UNIT  * 64;
    const ushort* enemy16 = emb16 + RO_ENEMY * 64;
    const ushort* skill16 = emb16 + RO_SKILL * 64;

    // ---- chunk-vectorized builder: unit u = (row r, 8-dim chunk un) ----
    for (int u = t; u < SROWS * 84; u += 256) {
        const int r  = u / 84;
        const int un = u - r * 84;
        const int b  = b0 + r;
        float* dst = s_in + r * SSTRIDE;
        if (un < 8) {                       // state_scalars
            const int o0 = un * 8;
            const float4 f0 = *(const float4*)(state_scalars + b * STATE_SC + o0);
            const float4 f1 = *(const float4*)(state_scalars + b * STATE_SC + o0 + 4);
            *(float4*)(dst + o0) = f0; *(float4*)(dst + o0 + 4) = f1;
        } else if (un < 16) {               // mode_emb
            const int d0 = (un - 8) * 8;
            const float4 f0 = *(const float4*)(mode_emb + mode_id[b] * DD + d0);
            const float4 f1 = *(const float4*)(mode_emb + mode_id[b] * DD + d0 + 4);
            *(float4*)(dst + 64 + d0) = f0; *(float4*)(dst + 64 + d0 + 4) = f1;
        } else if (un < 24) {               // hand_pool (bf16 card table)
            const int d0 = (un - 16) * 8;
            float acc[8] = {0,0,0,0,0,0,0,0}; int c = 0;
#pragma unroll
            for (int l = 0; l < L_HAND; ++l) {
                const int mk = hand_mask[b * L_HAND + l]; c += mk;
                const float fm = (float)mk;
                const short8 e = *(const short8*)(card16 + hand_ids[b * L_HAND + l] * 64 + d0);
#pragma unroll
                for (int q = 0; q < 8; ++q) acc[q] = fmaf(fm, bs2f(e[q]), acc[q]);
            }
            const float inv = 1.0f / (float)(c > 1 ? c : 1);
#pragma unroll
            for (int q = 0; q < 8; ++q) dst[128 + d0 + q] = acc[q] * inv;
        } else if (un < 32) {               // unit_pool
            const int d0 = (un - 24) * 8;
            float acc[8] = {0,0,0,0,0,0,0,0}; int c = 0;
#pragma unroll
            for (int l = 0; l < L_UNIT; ++l) {
                const int mk = unit_mask[b * L_UNIT + l]; c += mk;
                const float fm = (float)mk;
                const short8 e = *(const short8*)(unit16 + unit_ids[b * L_UNIT + l] * 64 + d0);
#pragma unroll
                for (int q = 0; q < 8; ++q) acc[q] = fmaf(fm, bs2f(e[q]), acc[q]);
            }
            const float inv = 1.0f / (float)(c > 1 ? c : 1);
#pragma unroll
            for (int q = 0; q < 8; ++q) dst[192 + d0 + q] = acc[q] * inv;
        } else if (un < 40) {               // terrain_emb
            const int d0 = (un - 32) * 8;
            const float4 f0 = *(const float4*)(ter_emb + terrain_id[b] * DD + d0);
            const float4 f1 = *(const float4*)(ter_emb + terrain_id[b] * DD + d0 + 4);
            *(float4*)(dst + 256 + d0) = f0; *(float4*)(dst + 256 + d0 + 4) = f1;
        } else if (un < 48) {               // site_emb
            const int d0 = (un - 40) * 8;
            const float4 f0 = *(const float4*)(site_emb + site_type_id[b] * DD + d0);
            const float4 f1 = *(const float4*)(site_emb + site_type_id[b] * DD + d0 + 4);
            *(float4*)(dst + 320 + d0) = f0; *(float4*)(dst + 320 + d0 + 4) = f1;
        } else if (un < 56) {               // ce_pool emb part
            const int d0 = (un - 48) * 8;
            float acc[8] = {0,0,0,0,0,0,0,0}; int c = 0;
#pragma unroll
            for (int l = 0; l < L_CE; ++l) {
                const int mk = ce_mask[b * L_CE + l]; c += mk;
                const float fm = (float)mk;
                const short8 e = *(const short8*)(enemy16 + ce_ids[b * L_CE + l] * 64 + d0);
#pragma unroll
                for (int q = 0; q < 8; ++q) acc[q] = fmaf(fm, bs2f(e[q]), acc[q]);
            }
            const float inv = 1.0f / (float)(c > 1 ? c : 1);
#pragma unroll
            for (int q = 0; q < 8; ++q) dst[384 + d0 + q] = acc[q] * inv;
        } else if (un == 56) {              // ce_pool scalar part (8)
            float acc[8] = {0,0,0,0,0,0,0,0}; int c = 0;
#pragma unroll
            for (int l = 0; l < L_CE; ++l) {
                const int mk = ce_mask[b * L_CE + l]; c += mk;
                const float fm = (float)mk;
                const float4 f0 = *(const float4*)(ce_sc + (b * L_CE + l) * CE_SC);
                const float4 f1 = *(const float4*)(ce_sc + (b * L_CE + l) * CE_SC + 4);
                acc[0] = fmaf(fm, f0.x, acc[0]); acc[1] = fmaf(fm, f0.y, acc[1]);
                acc[2] = fmaf(fm, f0.z, acc[2]); acc[3] = fmaf(fm, f0.w, acc[3]);
                acc[4] = fmaf(fm, f1.x, acc[4]); acc[5] = fmaf(fm, f1.y, acc[5]);
                acc[6] = fmaf(fm, f1.z, acc[6]); acc[7] = fmaf(fm, f1.w, acc[7]);
            }
            const float inv = 1.0f / (float)(c > 1 ? c : 1);
#pragma unroll
            for (int q = 0; q < 8; ++q) dst[448 + q] = acc[q] * inv;
        } else if (un < 65) {               // skill_pool
            const int d0 = (un - 57) * 8;
            float acc[8] = {0,0,0,0,0,0,0,0}; int c = 0;
#pragma unroll
            for (int l = 0; l < L_SK; ++l) {
                const int mk = skill_mask[b * L_SK + l]; c += mk;
                const float fm = (float)mk;
                const short8 e = *(const short8*)(skill16 + skill_ids[b * L_SK + l] * 64 + d0);
#pragma unroll
                for (int q = 0; q < 8; ++q) acc[q] = fmaf(fm, bs2f(e[q]), acc[q]);
            }
            const float inv = 1.0f / (float)(c > 1 ? c : 1);
#pragma unroll
            for (int q = 0; q < 8; ++q) dst[456 + d0 + q] = acc[q] * inv;
        } else if (un < 73) {               // vs_pool emb part (msite fp32)
            const int d0 = (un - 65) * 8;
            float acc[8] = {0,0,0,0,0,0,0,0}; int c = 0;
#pragma unroll
            for (int l = 0; l < L_VS; ++l) {
                const int mk = vs_mask[b * L_VS + l]; c += mk;
                const float fm = (float)mk;
                const float4 f0 = *(const float4*)(msite_emb + vs_ids[b * L_VS + l] * DD + d0);
                const float4 f1 = *(const float4*)(msite_emb + vs_ids[b * L_VS + l] * DD + d0 + 4);
                acc[0] = fmaf(fm, f0.x, acc[0]); acc[1] = fmaf(fm, f0.y, acc[1]);
                acc[2] = fmaf(fm, f0.z, acc[2]); acc[3] = fmaf(fm, f0.w, acc[3]);
                acc[4] = fmaf(fm, f1.x, acc[4]); acc[5] = fmaf(fm, f1.y, acc[5]);
                acc[6] = fmaf(fm, f1.z, acc[6]); acc[7] = fmaf(fm, f1.w, acc[7]);
            }
            const float inv = 1.0f / (float)(c > 1 ? c : 1);
#pragma unroll
            for (int q = 0; q < 8; ++q) dst[520 + d0 + q] = acc[q] * inv;
        } else if (un == 73) {              // vs_pool scalar part (6)
            float acc[6] = {0,0,0,0,0,0}; int c = 0;
#pragma unroll
            for (int l = 0; l < L_VS; ++l) {
                const int mk = vs_mask[b * L_VS + l]; c += mk;
                const float fm = (float)mk;
                const float* p = vs_sc + (b * L_VS + l) * SITE_SC;
#pragma unroll
                for (int q = 0; q < 6; ++q) acc[q] = fmaf(fm, p[q], acc[q]);
            }
            const float inv = 1.0f / (float)(c > 1 ? c : 1);
#pragma unroll
            for (int q = 0; q < 6; ++q) dst[584 + q] = acc[q] * inv;
        } else if (un < 82) {               // me_pool emb part (store at 590+d)
            const int d0 = (un - 74) * 8;
            float acc[8] = {0,0,0,0,0,0,0,0}; int c = 0;
#pragma unroll
            for (int l = 0; l < L_ME; ++l) {
                const int mk = me_mask[b * L_ME + l]; c += mk;
                const float fm = (float)mk;
                const short8 e = *(const short8*)(enemy16 + me_ids[b * L_ME + l] * 64 + d0);
#pragma unroll
                for (int q = 0; q < 8; ++q) acc[q] = fmaf(fm, bs2f(e[q]), acc[q]);
            }
            const float inv = 1.0f / (float)(c > 1 ? c : 1);
#pragma unroll
            for (int q = 0; q < 8; ++q) dst[590 + d0 + q] = acc[q] * inv;
        } else if (un == 82) {              // me_pool scalar part (8)
            float acc[8] = {0,0,0,0,0,0,0,0}; int c = 0;
#pragma unroll
            for (int l = 0; l < L_ME; ++l) {
                const int mk = me_mask[b * L_ME + l]; c += mk;
                const float fm = (float)mk;
                const float4 f0 = *(const float4*)(me_sc + (b * L_ME + l) * ME_SC);
                const float4 f1 = *(const float4*)(me_sc + (b * L_ME + l) * ME_SC + 4);
                acc[0] = fmaf(fm, f0.x, acc[0]); acc[1] = fmaf(fm, f0.y, acc[1]);
                acc[2] = fmaf(fm, f0.z, acc[2]); acc[3] = fmaf(fm, f0.w, acc[3]);
                acc[4] = fmaf(fm, f1.x, acc[4]); acc[5] = fmaf(fm, f1.y, acc[5]);
                acc[6] = fmaf(fm, f1.z, acc[6]); acc[7] = fmaf(fm, f1.w, acc[7]);
            }
            const float inv = 1.0f / (float)(c > 1 ? c : 1);
#pragma unroll
            for (int q = 0; q < 8; ++q) dst[654 + q] = acc[q] * inv;
        } else {                            // zero pad 662..671
#pragma unroll
            for (int q = 0; q < 10; ++q) dst[662 + q] = 0.f;
        }
    }
    __syncthreads();

    const short8* Ws8  = (const short8*)WsP;
    const short8* W1a8 = (const short8*)W1aP;
    const f32x4 zero = {0.f, 0.f, 0.f, 0.f};
    const int m15 = lane & 15;
    const int g = lane >> 4;
    const float* arow = s_in + (m15 & (SROWS - 1)) * SSTRIDE;

    // ---- GEMM1: state_input @ W_s over K=672 ----
    f32x4 acc1[4];
#pragma unroll
    for (int nt = 0; nt < 4; ++nt) acc1[nt] = zero;

    for (int kt = 0; kt < 21; ++kt) {
        const int k0 = kt * 32 + 8 * g;
        const float4 v0 = *(const float4*)(arow + k0);
        const float4 v1 = *(const float4*)(arow + k0 + 4);
        short8 a;
        a[0] = f2bs(v0.x); a[1] = f2bs(v0.y); a[2] = f2bs(v0.z); a[3] = f2bs(v0.w);
        a[4] = f2bs(v1.x); a[5] = f2bs(v1.y); a[6] = f2bs(v1.z); a[7] = f2bs(v1.w);
        short8 bfr[4];
#pragma unroll
        for (int nt = 0; nt < 4; ++nt) bfr[nt] = Ws8[(kt * 16 + w * 4 + nt) * 64 + lane];
#pragma unroll
        for (int nt = 0; nt < 4; ++nt)
            acc1[nt] = __builtin_amdgcn_mfma_f32_16x16x32_bf16(a, bfr[nt], acc1[nt], 0, 0, 0);
    }

    // ---- epilogue: tanh, value partials, A2 pack ----
    float sr[4][4];
    float pv[4] = {0.f, 0.f, 0.f, 0.f};
#pragma unroll
    for (int nt = 0; nt < 4; ++nt) {
        const int n = w * 64 + nt * 16 + m15;
        const float bsn = b_s[n];
        const float wvn = W_v[n];
#pragma unroll
        for (int r = 0; r < 4; ++r) {
            const float sv = fast_tanh(acc1[nt][r] + bsn);
            sr[nt][r] = sv;
            pv[r] = fmaf(sv, wvn, pv[r]);
        }
    }
#pragma unroll
    for (int r = 0; r < SROWS; ++r) {
        float v = pv[r];
        v += __shfl_xor(v, 1);
        v += __shfl_xor(v, 2);
        v += __shfl_xor(v, 4);
        v += __shfl_xor(v, 8);
        if (lane == 0) red[w][r] = v;
    }
    if (g == 0) {
#pragma unroll
        for (int nt = 0; nt < 4; ++nt) {
            const int n = w * 64 + nt * 16 + m15;
            const int kt2 = n >> 5;
            const int lo16 = (n >> 3) & 3;
#pragma unroll
            for (int r = 0; r < 4; ++r) {
                const int pi = (kt2 * 64 + (r + 16 * lo16)) * 8 + (n & 7);
                sA2[pi] = (ushort)f2bs(sr[nt][r]);
            }
        }
    }
    __syncthreads();

    if (t < SROWS) {
        out_value[b0 + t] = red[0][t] + red[1][t] + red[2][t] + red[3][t] + b_v[0];
    }

    // ---- GEMM2: state_repr @ W1[:256,:] over K=256 -> s_part fp32 ----
    const short8* sA2_8 = (const short8*)sA2;
    f32x4 acc2[4];
#pragma unroll
    for (int nt = 0; nt < 4; ++nt) acc2[nt] = zero;
#pragma unroll
    for (int kt = 0; kt < 8; ++kt) {
        const short8 a2 = sA2_8[kt * 64 + lane];
        short8 bfr[4];
#pragma unroll
        for (int nt = 0; nt < 4; ++nt) bfr[nt] = W1a8[(kt * 16 + w * 4 + nt) * 64 + lane];
#pragma unroll
        for (int nt = 0; nt < 4; ++nt)
            acc2[nt] = __builtin_amdgcn_mfma_f32_16x16x32_bf16(a2, bfr[nt], acc2[nt], 0, 0, 0);
    }
    if (g == 0) {
#pragma unroll
        for (int nt = 0; nt < 4; ++nt) {
            const int n = w * 64 + nt * 16 + m15;
#pragma unroll
            for (int r = 0; r < SROWS; ++r)
                s_part[(b0 + r) * HH + n] = acc2[nt][r];
        }
    }
}

// ---- action A1 TAIL chunk (k0 >= 384): tgt_pool / scalars / pad ----
__device__ __forceinline__ short8 tail_chunk(
    int k0, int m, int b,
    const int* __restrict__ tgt_ids, const int* __restrict__ tgt_mask,
    const ushort* __restrict__ emb16, const float* __restrict__ action_scalars)
{
    short8 val;
    if (k0 < 448) {
        const int d = k0 - 384;
        const ushort* enemy16 = emb16 + RO_ENEMY * 64;
        const int base = (b * NN + m) * L_TGT;
        const int4 t0v = *(const int4*)(tgt_ids + base);
        const int4 t1v = *(const int4*)(tgt_ids + base + 4);
        const int4 m0v = *(const int4*)(tgt_mask + base);
        const int4 m1v = *(const int4*)(tgt_mask + base + 4);
        const int tid[8] = {t0v.x, t0v.y, t0v.z, t0v.w, t1v.x, t1v.y, t1v.z, t1v.w};
        const int tmk[8] = {m0v.x, m0v.y, m0v.z, m0v.w, m1v.x, m1v.y, m1v.z, m1v.w};
        float accq[8] = {0.f, 0.f, 0.f, 0.f, 0.f, 0.f, 0.f, 0.f};
        int c = 0;
#pragma unroll
        for (int l = 0; l < L_TGT; ++l) {
            const int mk = tmk[l];
            c += mk;
            const float fm = (float)mk;
            const short8 e = *(const short8*)(enemy16 + tid[l] * 64 + d);
#pragma unroll
            for (int q = 0; q < 8; ++q) accq[q] = fmaf(fm, bs2f(e[q]), accq[q]);
        }
        const float inv = 1.0f / (float)(c > 1 ? c : 1);
#pragma unroll
        for (int q = 0; q < 8; ++q) val[q] = f2bs(accq[q] * inv);
    } else if (k0 < 464) {
        const float* sc = action_scalars + (b * NN + m) * ACT_SC + (k0 - 448);
        const float4 f0 = *(const float4*)sc;
        const float4 f1 = *(const float4*)(sc + 4);
        val[0] = f2bs(f0.x); val[1] = f2bs(f0.y); val[2] = f2bs(f0.z); val[3] = f2bs(f0.w);
        val[4] = f2bs(f1.x); val[5] = f2bs(f1.y); val[6] = f2bs(f1.z); val[7] = f2bs(f1.w);
    } else {
#pragma unroll
        for (int q = 0; q < 8; ++q) val[q] = 0;
    }
    return val;
}

// ===================== MFMA action kernel (512 threads, 8 waves, 2 batch rows) ====
// Waves 0..3 -> row b0, waves 4..7 -> row b0+1; wave-in-row wr owns 64 N-cols
// (acc[4][4]). Per-row 9-tile A1 buffer (phase-1 DMA kt 0..5; tail kt 12..14 ->
// tiles 6..8; phase-2 DMA kt 6..11; A2 reuses tiles 0..7). The two wave-groups
// read IDENTICAL W fragments back-to-back -> L1-coalesced, halving W L2 traffic;
// block count halves -> per-block barrier/DMA chains amortized over 2x work.
__global__ __launch_bounds__(512) void action_mfma_kernel(
    const int* __restrict__ action_ids, const float* __restrict__ action_scalars,
    const int* __restrict__ tgt_ids, const int* __restrict__ tgt_mask,
    const ushort* __restrict__ emb16,
    const ushort* __restrict__ WaP, const float* __restrict__ b_a,
    const ushort* __restrict__ W1bP, const float* __restrict__ b1,
    const float* __restrict__ W2, const float* __restrict__ b2,
    const float* __restrict__ s_part, float* __restrict__ out_logits)
{
    __shared__ ushort sA[2 * 9 * 2048];    // 73,728 B: 2 rows x 9 MFMA tiles
    __shared__ float red[8][64];           // 2,048 B
    __shared__ int s_ids[2 * 64 * 6];      // 3,072 B  (total 78,848 B)

    const int t = threadIdx.x;
    const int b0 = blockIdx.x * 2;
    const int w = t >> 6;        // wave 0..7
    const int r = w >> 2;        // batch-row within block
    const int wr = w & 3;        // wave-in-row, owns cols wr*64 .. wr*64+63
    const int b = b0 + r;
    const int lane = t & 63;
    const int m15 = lane & 15;

    ushort* sAr = sA + r * 9 * 2048;
    const short8* sA8  = (const short8*)sAr;
    short8* sA8w = (short8*)sAr;
    const int* idsr = s_ids + r * 64 * 6;
    const short8* Wa8  = (const short8*)WaP;
    const short8* W1b8 = (const short8*)W1bP;
    const f32x4 zero = {0.f, 0.f, 0.f, 0.f};

    // initial B prefetch (kt 0) — independent of LDS
    short8 bn0 = Wa8[(wr * 4 + 0) * 64 + lane];
    short8 bn1 = Wa8[(wr * 4 + 1) * 64 + lane];
    short8 bn2 = Wa8[(wr * 4 + 2) * 64 + lane];
    short8 bn3 = Wa8[(wr * 4 + 3) * 64 + lane];

    // ---- stage action ids for both rows (coalesced) ----
    for (int i = t; i < 2 * 64 * 6; i += 512) s_ids[i] = action_ids[b0 * (64 * 6) + i];
    __syncthreads();   // B1

    const int ROFFS[6] = {RO_AT, RO_SRC, RO_CARD, RO_UNIT, RO_ENEMY, RO_SKILL};

    // ---- phase-1 DMA: stage emb kt 0..5 -> row tiles 0..5 ----
    {
        const int kt = wr;                         // wr 0..3 -> tiles 0..3
        const int j = kt >> 1;
        const int koff = (kt & 1) * 32 + (lane >> 4) * 8;
#pragma unroll
        for (int i = 0; i < 4; ++i) {
            const int id = idsr[(i * 16 + m15) * 6 + j];
            async_copy16(emb16 + (ROFFS[j] + id) * 64 + koff, sAr + kt * 2048 + i * 512);
        }
    }
    if (wr < 2) {
        const int kt = 4 + wr;                     // wr 0..1 -> tiles 4..5
        const int j = kt >> 1;
        const int koff = (kt & 1) * 32 + (lane >> 4) * 8;
#pragma unroll
        for (int i = 0; i < 4; ++i) {
            const int id = idsr[(i * 16 + m15) * 6 + j];
            async_copy16(emb16 + (ROFFS[j] + id) * 64 + koff, sAr + kt * 2048 + i * 512);
        }
    }

    // ---- tail build (kt 12..14 -> row tiles 6..8) while DMA is in flight ----
    {
        const int m = lane;
        const int mt_b = m >> 4, mrow = m & 15;
        for (int kc = 48 + wr; kc < 60; kc += 4) {
            const int k0 = kc << 3;
            const short8 val = tail_chunk(k0, m, b, tgt_ids, tgt_mask, emb16, action_scalars);
            const int ktl = (k0 >> 5) - 6;         // tiles 6..8
            const int lo = kc & 3;
            sA8w[(ktl * 4 + mt_b) * 64 + mrow + 16 * lo] = val;
        }
    }
    __syncthreads();   // B2: phase-1 DMA + tail landed

    // epilogue-1 bias, loaded early
    float ba[4];
#pragma unroll
    for (int nt = 0; nt < 4; ++nt) ba[nt] = b_a[wr * 64 + nt * 16 + m15];

    f32x4 acc[4][4];
#pragma unroll
    for (int i = 0; i < 4; ++i)
#pragma unroll
        for (int j = 0; j < 4; ++j) acc[i][j] = zero;

    // ---- GEMM1 loop A: kt 0..5 (tiles 0..5) ----
#pragma unroll
    for (int kt = 0; kt < 6; ++kt) {
        const short8 b0v = bn0, b1v = bn1, b2v = bn2, b3v = bn3;
        const int nkt = (kt < 5) ? kt + 1 : 12;
        bn0 = Wa8[(nkt * 16 + wr * 4 + 0) * 64 + lane];
        bn1 = Wa8[(nkt * 16 + wr * 4 + 1) * 64 + lane];
        bn2 = Wa8[(nkt * 16 + wr * 4 + 2) * 64 + lane];
        bn3 = Wa8[(nkt * 16 + wr * 4 + 3) * 64 + lane];
        short8 a[4];
#pragma unroll
        for (int mti = 0; mti < 4; ++mti) a[mti] = sA8[(kt * 4 + mti) * 64 + lane];
        __builtin_amdgcn_s_setprio(1);
#pragma unroll
        for (int mti = 0; mti < 4; ++mti) {
            acc[mti][0] = __builtin_amdgcn_mfma_f32_16x16x32_bf16(a[mti], b0v, acc[mti][0], 0, 0, 0);
            acc[mti][1] = __builtin_amdgcn_mfma_f32_16x16x32_bf16(a[mti], b1v, acc[mti][1], 0, 0, 0);
            acc[mti][2] = __builtin_amdgcn_mfma_f32_16x16x32_bf16(a[mti], b2v, acc[mti][2], 0, 0, 0);
            acc[mti][3] = __builtin_amdgcn_mfma_f32_16x16x32_bf16(a[mti], b3v, acc[mti][3], 0, 0, 0);
        }
        __builtin_amdgcn_s_setprio(0);
    }
    __syncthreads();   // B3: all waves done reading their row tiles 0..5

    // ---- phase-2 DMA: stage emb kt 6..11 -> row tiles 0..5 ----
    {
        const int kt = 6 + wr;                     // wr 0..3 -> tiles 0..3
        const int j = kt >> 1;
        const int koff = (kt & 1) * 32 + (lane >> 4) * 8;
#pragma unroll
        for (int i = 0; i < 4; ++i) {
            const int id = idsr[(i * 16 + m15) * 6 + j];
            async_copy16(emb16 + (ROFFS[j] + id) * 64 + koff, sAr + (kt - 6) * 2048 + i * 512);
        }
    }
    if (wr < 2) {
        const int kt = 10 + wr;                    // wr 0..1 -> tiles 4..5
        const int j = kt >> 1;
        const int koff = (kt & 1) * 32 + (lane >> 4) * 8;
#pragma unroll
        for (int i = 0; i < 4; ++i) {
            const int id = idsr[(i * 16 + m15) * 6 + j];
            async_copy16(emb16 + (ROFFS[j] + id) * 64 + koff, sAr + (kt - 6) * 2048 + i * 512);
        }
    }

    // ---- GEMM1 loop B: kt 12..14 (tail tiles 6..8) — overlaps phase-2 DMA ----
#pragma unroll
    for (int kt = 12; kt < 15; ++kt) {
        const short8 b0v = bn0, b1v = bn1, b2v = bn2, b3v = bn3;
        const int nkt = (kt < 14) ? kt + 1 : 6;
        bn0 = Wa8[(nkt * 16 + wr * 4 + 0) * 64 + lane];
        bn1 = Wa8[(nkt * 16 + wr * 4 + 1) * 64 + lane];
        bn2 = Wa8[(nkt * 16 + wr * 4 + 2) * 64 + lane];
        bn3 = Wa8[(nkt * 16 + wr * 4 + 3) * 64 + lane];
        short8 a[4];
#pragma unroll
        for (int mti = 0; mti < 4; ++mti) a[mti] = sA8[((kt - 6) * 4 + mti) * 64 + lane];
        __builtin_amdgcn_s_setprio(1);
#pragma unroll
        for (int mti = 0; mti < 4; ++mti) {
            acc[mti][0] = __builtin_amdgcn_mfma_f32_16x16x32_bf16(a[mti], b0v, acc[mti][0], 0, 0, 0);
            acc[mti][1] = __builtin_amdgcn_mfma_f32_16x16x32_bf16(a[mti], b1v, acc[mti][1], 0, 0, 0);
            acc[mti][2] = __builtin_amdgcn_mfma_f32_16x16x32_bf16(a[mti], b2v, acc[mti][2], 0, 0, 0);
            acc[mti][3] = __builtin_amdgcn_mfma_f32_16x16x32_bf16(a[mti], b3v, acc[mti][3], 0, 0, 0);
        }
        __builtin_amdgcn_s_setprio(0);
    }
    __syncthreads();   // B4: drains phase-2 DMA

    // ---- GEMM1 loop C: kt 6..11 (tiles 0..5) ----
    short8 cn0, cn1, cn2, cn3;
#pragma unroll
    for (int kt = 6; kt < 12; ++kt) {
        const short8 b0v = bn0, b1v = bn1, b2v = bn2, b3v = bn3;
        if (kt < 11) {
            bn0 = Wa8[((kt + 1) * 16 + wr * 4 + 0) * 64 + lane];
            bn1 = Wa8[((kt + 1) * 16 + wr * 4 + 1) * 64 + lane];
            bn2 = Wa8[((kt + 1) * 16 + wr * 4 + 2) * 64 + lane];
            bn3 = Wa8[((kt + 1) * 16 + wr * 4 + 3) * 64 + lane];
        } else {
            cn0 = W1b8[(wr * 4 + 0) * 64 + lane];  // GEMM2 kt0 prefetch
            cn1 = W1b8[(wr * 4 + 1) * 64 + lane];
            cn2 = W1b8[(wr * 4 + 2) * 64 + lane];
            cn3 = W1b8[(wr * 4 + 3) * 64 + lane];
        }
        short8 a[4];
#pragma unroll
        for (int mti = 0; mti < 4; ++mti) a[mti] = sA8[((kt - 6) * 4 + mti) * 64 + lane];
        __builtin_amdgcn_s_setprio(1);
#pragma unroll
        for (int mti = 0; mti < 4; ++mti) {
            acc[mti][0] = __builtin_amdgcn_mfma_f32_16x16x32_bf16(a[mti], b0v, acc[mti][0], 0, 0, 0);
            acc[mti][1] = __builtin_amdgcn_mfma_f32_16x16x32_bf16(a[mti], b1v, acc[mti][1], 0, 0, 0);
            acc[mti][2] = __builtin_amdgcn_mfma_f32_16x16x32_bf16(a[mti], b2v, acc[mti][2], 0, 0, 0);
            acc[mti][3] = __builtin_amdgcn_mfma_f32_16x16x32_bf16(a[mti], b3v, acc[mti][3], 0, 0, 0);
        }
        __builtin_amdgcn_s_setprio(0);
    }
    __syncthreads();   // B5: all A1 reads done before writing A2

    // ---- epilogue 1: action_repr = tanh(acc + b_a) -> packed A2 (row tiles 0..7) ----
#pragma unroll
    for (int mti = 0; mti < 4; ++mti)
#pragma unroll
        for (int nt = 0; nt < 4; ++nt) {
            const int n = wr * 64 + nt * 16 + m15;      // GEMM2 k-dim
            const int kt2 = n >> 5;
            const int lo16 = (n >> 3) & 3;
#pragma unroll
            for (int rr = 0; rr < 4; ++rr) {
                const int mm = mti * 16 + (lane >> 4) * 4 + rr;
                const float h = fast_tanh(acc[mti][nt][rr] + ba[nt]);
                const int pi = ((kt2 * 4 + mti) * 64 + ((mm & 15) + 16 * lo16)) * 8 + (n & 7);
                sAr[pi] = (ushort)f2bs(h);
            }
        }
    __syncthreads();   // B6: A2 ready

    // epilogue-2 constants, loaded early (latency hides under GEMM2)
    float sp[4], w2v[4];
#pragma unroll
    for (int nt = 0; nt < 4; ++nt) {
        const int n = wr * 64 + nt * 16 + m15;
        sp[nt]  = s_part[b * HH + n] + b1[n];
        w2v[nt] = W2[n];
    }

    // ---- GEMM2: K=256, A from row tiles 0..7, B prefetched ----
#pragma unroll
    for (int i = 0; i < 4; ++i)
#pragma unroll
        for (int j = 0; j < 4; ++j) acc[i][j] = zero;

#pragma unroll
    for (int kt = 0; kt < 8; ++kt) {
        const short8 b0v = cn0, b1v = cn1, b2v = cn2, b3v = cn3;
        if (kt < 7) {
            cn0 = W1b8[((kt + 1) * 16 + wr * 4 + 0) * 64 + lane];
            cn1 = W1b8[((kt + 1) * 16 + wr * 4 + 1) * 64 + lane];
            cn2 = W1b8[((kt + 1) * 16 + wr * 4 + 2) * 64 + lane];
            cn3 = W1b8[((kt + 1) * 16 + wr * 4 + 3) * 64 + lane];
        }
        short8 a[4];
#pragma unroll
        for (int mti = 0; mti < 4; ++mti) a[mti] = sA8[(kt * 4 + mti) * 64 + lane];
        __builtin_amdgcn_s_setprio(1);
#pragma unroll
        for (int mti = 0; mti < 4; ++mti) {
            acc[mti][0] = __builtin_amdgcn_mfma_f32_16x16x32_bf16(a[mti], b0v, acc[mti][0], 0, 0, 0);
            acc[mti][1] = __builtin_amdgcn_mfma_f32_16x16x32_bf16(a[mti], b1v, acc[mti][1], 0, 0, 0);
            acc[mti][2] = __builtin_amdgcn_mfma_f32_16x16x32_bf16(a[mti], b2v, acc[mti][2], 0, 0, 0);
            acc[mti][3] = __builtin_amdgcn_mfma_f32_16x16x32_bf16(a[mti], b3v, acc[mti][3], 0, 0, 0);
        }
        __builtin_amdgcn_s_setprio(0);
    }

    // ---- epilogue 2: logits[m] = sum_n tanh(acc + s_part + b1) * W2[n] + b2 ----
    float part[4][4];
#pragma unroll
    for (int mti = 0; mti < 4; ++mti)
#pragma unroll
        for (int rr = 0; rr < 4; ++rr) part[mti][rr] = 0.f;

#pragma unroll
    for (int mti = 0; mti < 4; ++mti)
#pragma unroll
        for (int nt = 0; nt < 4; ++nt)
#pragma unroll
            for (int rr = 0; rr < 4; ++rr)
                part[mti][rr] += fast_tanh(acc[mti][nt][rr] + sp[nt]) * w2v[nt];

    // DPP row-sum over the 16 col-lanes; lane m15==15 holds it
#pragma unroll
    for (int mti = 0; mti < 4; ++mti)
#pragma unroll
        for (int rr = 0; rr < 4; ++rr)
            part[mti][rr] = sum16_dpp(part[mti][rr]);

    if (m15 == 15) {
#pragma unroll
        for (int mti = 0; mti < 4; ++mti)
#pragma unroll
            for (int rr = 0; rr < 4; ++rr) {
                const int mm = mti * 16 + (lane >> 4) * 4 + rr;
                red[w][mm] = part[mti][rr];
            }
    }
    __syncthreads();   // B7
    if (t < 128) {
        const int rr = t >> 6, m = t & 63;
        out_logits[(b0 + rr) * NN + m] =
            red[rr * 4 + 0][m] + red[rr * 4 + 1][m] + red[rr * 4 + 2][m] + red[rr * 4 + 3][m] + b2[0];
    }
}

extern "C" void kernel_launch(void* const* d_in, const int* in_sizes, int n_in,
                              void* d_out, int out_size, void* d_ws, size_t ws_size,
                              hipStream_t stream) {
    const float* state_scalars = (const float*)d_in[0];
    const int*   mode_id       = (const int*)d_in[1];
    const int*   terrain_id    = (const int*)d_in[2];
    const int*   site_type_id  = (const int*)d_in[3];
    const int*   hand_ids      = (const int*)d_in[4];
    const int*   hand_mask     = (const int*)d_in[5];
    const int*   unit_ids      = (const int*)d_in[6];
    const int*   unit_mask     = (const int*)d_in[7];
    const int*   ce_ids        = (const int*)d_in[8];
    const float* ce_sc         = (const float*)d_in[9];
    const int*   ce_mask       = (const int*)d_in[10];
    const int*   skill_ids     = (const int*)d_in[11];
    const int*   skill_mask    = (const int*)d_in[12];
    const int*   vs_ids        = (const int*)d_in[13];
    const float* vs_sc         = (const float*)d_in[14];
    const int*   vs_mask       = (const int*)d_in[15];
    const int*   me_ids        = (const int*)d_in[16];
    const float* me_sc         = (const float*)d_in[17];
    const int*   me_mask       = (const int*)d_in[18];
    const int*   action_ids    = (const int*)d_in[19];
    const float* action_scalars= (const float*)d_in[20];
    const int*   tgt_ids       = (const int*)d_in[21];
    const int*   tgt_mask      = (const int*)d_in[22];
    const float* card_emb      = (const float*)d_in[23];
    const float* unit_emb      = (const float*)d_in[24];
    const float* enemy_emb     = (const float*)d_in[25];
    const float* at_emb        = (const float*)d_in[26];
    const float* src_emb       = (const float*)d_in[27];
    const float* mode_emb      = (const float*)d_in[28];
    const float* ter_emb       = (const float*)d_in[29];
    const float* site_emb      = (const float*)d_in[30];
    const float* skill_emb     = (const float*)d_in[31];
    const float* msite_emb     = (const float*)d_in[32];
    const float* W_s           = (const float*)d_in[33];
    const float* b_s           = (const float*)d_in[34];
    const float* W_a           = (const float*)d_in[35];
    const float* b_a           = (const float*)d_in[36];
    const float* W1            = (const float*)d_in[37];
    const float* b1            = (const float*)d_in[38];
    const float* W2            = (const float*)d_in[39];
    const float* b2            = (const float*)d_in[40];
    const float* W_v           = (const float*)d_in[41];
    const float* b_v           = (const float*)d_in[42];

    float* out_logits = (float*)d_out;                   // [B, N]
    float* out_value  = (float*)d_out + (size_t)BB * NN; // [B]

    // workspace layout (16B-aligned sections)
    char* ws = (char*)d_ws;
    float*  s_part = (float*)ws;                          // 2,097,152 B
    ushort* WaP    = (ushort*)(ws + 2097152);             // 245,760 B
    ushort* W1bP   = (ushort*)(ws + 2342912);             // 131,072 B
    ushort* emb16  = (ushort*)(ws + 2473984);             //  97,280 B
    ushort* WsP    = (ushort*)(ws + 2571264);             // 344,064 B
    ushort* W1aP   = (ushort*)(ws + 2915328);             // 131,072 B (end 3,046,400)

    pack_kernel<<<(T4 + 255) / 256, 256, 0, stream>>>(
        W_a, W1, W_s, at_emb, src_emb, card_emb, unit_emb, enemy_emb, skill_emb,
        WaP, W1bP, emb16, WsP, W1aP);

    state_mfma_kernel<<<BB / SROWS, 256, 0, stream>>>(
        state_scalars, mode_id, terrain_id, site_type_id,
        hand_ids, hand_mask, unit_ids, unit_mask,
        ce_ids, ce_sc, ce_mask, skill_ids, skill_mask,
        vs_ids, vs_sc, vs_mask, me_ids, me_sc, me_mask,
        mode_emb, ter_emb, site_emb, msite_emb, emb16,
        WsP, b_s, W1aP, W_v, b_v, s_part, out_value);

    action_mfma_kernel<<<BB / 2, 512, 0, stream>>>(
        action_ids, action_scalars, tgt_ids, tgt_mask,
        emb16, WaP, b_a, W1bP, b1, W2, b2, s_part, out_logits);
}

// Round 14
// 109.689 us; speedup vs baseline: 1.0741x; 1.0741x over previous
//
#include <hip/hip_runtime.h>
#include <hip/hip_bf16.h>

// ---- problem constants (match reference) ----
#define BB 2048
#define NN 64
#define DD 64
#define HH 256
#define L_HAND 16
#define L_UNIT 8
#define L_CE 8
#define L_SK 8
#define L_VS 16
#define L_ME 16
#define L_TGT 8
#define STATE_SC 64
#define CE_SC 8
#define SITE_SC 6
#define ME_SC 8
#define ACT_SC 16
#define STATE_IN 662
#define ACT_IN 464

#define SROWS 2      // batch rows per block in state kernel
#define SK 672       // state K padded to 21*32
#define SSTRIDE 676  // fp32 LDS row stride

typedef __attribute__((ext_vector_type(8))) short short8;   // 8 bf16 = 4 VGPRs
typedef __attribute__((ext_vector_type(4))) float f32x4;    // MFMA accum

__device__ __forceinline__ float fast_tanh(float x) {
    float e = __expf(2.0f * x);
    return 1.0f - 2.0f * __builtin_amdgcn_rcpf(e + 1.0f);
}
__device__ __forceinline__ short f2bs(float x) {
    __hip_bfloat16 h = __float2bfloat16(x);
    return *reinterpret_cast<short*>(&h);
}
__device__ __forceinline__ float bs2f(short u) {
    union { unsigned int i; float f; } v;
    v.i = ((unsigned int)(unsigned short)u) << 16;
    return v.f;
}
// async global->LDS 16B per lane: per-lane global src, wave-uniform LDS base
__device__ __forceinline__ void async_copy16(const void* gsrc, void* ldst) {
    __builtin_amdgcn_global_load_lds(
        (const __attribute__((address_space(1))) unsigned int*)gsrc,
        (__attribute__((address_space(3))) unsigned int*)ldst, 16, 0, 0);
}
// sum over each 16-lane row via DPP row_shr adds; lane (l&15)==15 holds the sum
__device__ __forceinline__ float sum16_dpp(float v) {
    int x;
    x = __builtin_amdgcn_update_dpp(0, __float_as_int(v), 0x111, 0xf, 0xf, true);
    v += __int_as_float(x);
    x = __builtin_amdgcn_update_dpp(0, __float_as_int(v), 0x112, 0xf, 0xf, true);
    v += __int_as_float(x);
    x = __builtin_amdgcn_update_dpp(0, __float_as_int(v), 0x114, 0xf, 0xf, true);
    v += __int_as_float(x);
    x = __builtin_amdgcn_update_dpp(0, __float_as_int(v), 0x118, 0xf, 0xf, true);
    v += __int_as_float(x);
    return v;
}

// emb16 row offsets: at(50), src(30), card(400), unit(100), enemy(120), skill(60)
#define RO_AT    0
#define RO_SRC   50
#define RO_CARD  80
#define RO_UNIT  480
#define RO_ENEMY 580
#define RO_SKILL 700
#define EMB_ROWS 760

// pack segment boundaries
#define T0 (480 * 256)            // WaP
#define T1 (T0 + 256 * 256)       // W1bP
#define T2 (T1 + EMB_ROWS * 64)   // emb16
#define T3 (T2 + SK * 256)        // WsP
#define T4 (T3 + 256 * 256)       // W1aP

// ===================== weight + embedding pre-pack kernel =====================
__global__ __launch_bounds__(256) void pack_kernel(
    const float* __restrict__ W_a, const float* __restrict__ W1,
    const float* __restrict__ W_s,
    const float* __restrict__ at_emb, const float* __restrict__ src_emb,
    const float* __restrict__ card_emb, const float* __restrict__ unit_emb,
    const float* __restrict__ enemy_emb, const float* __restrict__ skill_emb,
    ushort* __restrict__ WaP, ushort* __restrict__ W1bP, ushort* __restrict__ emb16,
    ushort* __restrict__ WsP, ushort* __restrict__ W1aP)
{
    const int idx = blockIdx.x * 256 + threadIdx.x;
    if (idx < T0) {
        const int k = idx >> 8, n = idx & 255;
        const float v = (k < ACT_IN) ? W_a[k * HH + n] : 0.f;
        const int pi = (((k >> 5) * 16 + (n >> 4)) * 64 +
                        ((n & 15) + 16 * ((k >> 3) & 3))) * 8 + (k & 7);
        WaP[pi] = (ushort)f2bs(v);
    } else if (idx < T1) {
        const int j = idx - T0;
        const int k = j >> 8, n = j & 255;
        const float v = W1[(256 + k) * HH + n];
        const int pi = (((k >> 5) * 16 + (n >> 4)) * 64 +
                        ((n & 15) + 16 * ((k >> 3) & 3))) * 8 + (k & 7);
        W1bP[pi] = (ushort)f2bs(v);
    } else if (idx < T2) {
        const int j = idx - T1;
        const int row = j >> 6, d = j & 63;
        float v;
        if      (row < RO_SRC)   v = at_emb[row * 64 + d];
        else if (row < RO_CARD)  v = src_emb[(row - RO_SRC) * 64 + d];
        else if (row < RO_UNIT)  v = card_emb[(row - RO_CARD) * 64 + d];
        else if (row < RO_ENEMY) v = unit_emb[(row - RO_UNIT) * 64 + d];
        else if (row < RO_SKILL) v = enemy_emb[(row - RO_ENEMY) * 64 + d];
        else                     v = skill_emb[(row - RO_SKILL) * 64 + d];
        emb16[j] = (ushort)f2bs(v);
    } else if (idx < T3) {
        const int j = idx - T2;
        const int k = j >> 8, n = j & 255;
        const float v = (k < STATE_IN) ? W_s[k * HH + n] : 0.f;
        const int pi = (((k >> 5) * 16 + (n >> 4)) * 64 +
                        ((n & 15) + 16 * ((k >> 3) & 3))) * 8 + (k & 7);
        WsP[pi] = (ushort)f2bs(v);
    } else if (idx < T4) {
        const int j = idx - T3;
        const int k = j >> 8, n = j & 255;
        const float v = W1[k * HH + n];   // first (state) half of W1
        const int pi = (((k >> 5) * 16 + (n >> 4)) * 64 +
                        ((n & 15) + 16 * ((k >> 3) & 3))) * 8 + (k & 7);
        W1aP[pi] = (ushort)f2bs(v);
    }
}

// ===================== state encoding kernel (MFMA, chunk-vectorized builder) ====
__global__ __launch_bounds__(256) void state_mfma_kernel(
    const float* __restrict__ state_scalars,
    const int* __restrict__ mode_id, const int* __restrict__ terrain_id,
    const int* __restrict__ site_type_id,
    const int* __restrict__ hand_ids, const int* __restrict__ hand_mask,
    const int* __restrict__ unit_ids, const int* __restrict__ unit_mask,
    const int* __restrict__ ce_ids, const float* __restrict__ ce_sc, const int* __restrict__ ce_mask,
    const int* __restrict__ skill_ids, const int* __restrict__ skill_mask,
    const int* __restrict__ vs_ids, const float* __restrict__ vs_sc, const int* __restrict__ vs_mask,
    const int* __restrict__ me_ids, const float* __restrict__ me_sc, const int* __restrict__ me_mask,
    const float* __restrict__ mode_emb, const float* __restrict__ ter_emb,
    const float* __restrict__ site_emb, const float* __restrict__ msite_emb,
    const ushort* __restrict__ emb16,
    const ushort* __restrict__ WsP, const float* __restrict__ b_s,
    const ushort* __restrict__ W1aP,
    const float* __restrict__ W_v, const float* __restrict__ b_v,
    float* __restrict__ s_part, float* __restrict__ out_value)
{
    __shared__ float s_in[SROWS * SSTRIDE];   // 5,408 B
    __shared__ ushort sA2[8 * 64 * 8];        // 8,192 B (GEMM2 A, bf16 packed)
    __shared__ float red[4][4];

    const int t = threadIdx.x;
    const int b0 = blockIdx.x * SROWS;
    const int w = t >> 6;
    const int lane = t & 63;
    const ushort* card16  = emb16 + RO_CARD  * 64;
    const ushort* unit16  = emb16 + RO_UNIT  * 64;
    const ushort* enemy16 = emb16 + RO_ENEMY * 64;
    const ushort* skill16 = emb16 + RO_SKILL * 64;

    // ---- chunk-vectorized builder: unit u = (row r, 8-dim chunk un) ----
    for (int u = t; u < SROWS * 84; u += 256) {
        const int r  = u / 84;
        const int un = u - r * 84;
        const int b  = b0 + r;
        float* dst = s_in + r * SSTRIDE;
        if (un < 8) {                       // state_scalars
            const int o0 = un * 8;
            const float4 f0 = *(const float4*)(state_scalars + b * STATE_SC + o0);
            const float4 f1 = *(const float4*)(state_scalars + b * STATE_SC + o0 + 4);
            *(float4*)(dst + o0) = f0; *(float4*)(dst + o0 + 4) = f1;
        } else if (un < 16) {               // mode_emb
            const int d0 = (un - 8) * 8;
            const float4 f0 = *(const float4*)(mode_emb + mode_id[b] * DD + d0);
            const float4 f1 = *(const float4*)(mode_emb + mode_id[b] * DD + d0 + 4);
            *(float4*)(dst + 64 + d0) = f0; *(float4*)(dst + 64 + d0 + 4) = f1;
        } else if (un < 24) {               // hand_pool (bf16 card table)
            const int d0 = (un - 16) * 8;
            float acc[8] = {0,0,0,0,0,0,0,0}; int c = 0;
#pragma unroll
            for (int l = 0; l < L_HAND; ++l) {
                const int mk = hand_mask[b * L_HAND + l]; c += mk;
                const float fm = (float)mk;
                const short8 e = *(const short8*)(card16 + hand_ids[b * L_HAND + l] * 64 + d0);
#pragma unroll
                for (int q = 0; q < 8; ++q) acc[q] = fmaf(fm, bs2f(e[q]), acc[q]);
            }
            const float inv = 1.0f / (float)(c > 1 ? c : 1);
#pragma unroll
            for (int q = 0; q < 8; ++q) dst[128 + d0 + q] = acc[q] * inv;
        } else if (un < 32) {               // unit_pool
            const int d0 = (un - 24) * 8;
            float acc[8] = {0,0,0,0,0,0,0,0}; int c = 0;
#pragma unroll
            for (int l = 0; l < L_UNIT; ++l) {
                const int mk = unit_mask[b * L_UNIT + l]; c += mk;
                const float fm = (float)mk;
                const short8 e = *(const short8*)(unit16 + unit_ids[b * L_UNIT + l] * 64 + d0);
#pragma unroll
                for (int q = 0; q < 8; ++q) acc[q] = fmaf(fm, bs2f(e[q]), acc[q]);
            }
            const float inv = 1.0f / (float)(c > 1 ? c : 1);
#pragma unroll
            for (int q = 0; q < 8; ++q) dst[192 + d0 + q] = acc[q] * inv;
        } else if (un < 40) {               // terrain_emb
            const int d0 = (un - 32) * 8;
            const float4 f0 = *(const float4*)(ter_emb + terrain_id[b] * DD + d0);
            const float4 f1 = *(const float4*)(ter_emb + terrain_id[b] * DD + d0 + 4);
            *(float4*)(dst + 256 + d0) = f0; *(float4*)(dst + 256 + d0 + 4) = f1;
        } else if (un < 48) {               // site_emb
            const int d0 = (un - 40) * 8;
            const float4 f0 = *(const float4*)(site_emb + site_type_id[b] * DD + d0);
            const float4 f1 = *(const float4*)(site_emb + site_type_id[b] * DD + d0 + 4);
            *(float4*)(dst + 320 + d0) = f0; *(float4*)(dst + 320 + d0 + 4) = f1;
        } else if (un < 56) {               // ce_pool emb part
            const int d0 = (un - 48) * 8;
            float acc[8] = {0,0,0,0,0,0,0,0}; int c = 0;
#pragma unroll
            for (int l = 0; l < L_CE; ++l) {
                const int mk = ce_mask[b * L_CE + l]; c += mk;
                const float fm = (float)mk;
                const short8 e = *(const short8*)(enemy16 + ce_ids[b * L_CE + l] * 64 + d0);
#pragma unroll
                for (int q = 0; q < 8; ++q) acc[q] = fmaf(fm, bs2f(e[q]), acc[q]);
            }
            const float inv = 1.0f / (float)(c > 1 ? c : 1);
#pragma unroll
            for (int q = 0; q < 8; ++q) dst[384 + d0 + q] = acc[q] * inv;
        } else if (un == 56) {              // ce_pool scalar part (8)
            float acc[8] = {0,0,0,0,0,0,0,0}; int c = 0;
#pragma unroll
            for (int l = 0; l < L_CE; ++l) {
                const int mk = ce_mask[b * L_CE + l]; c += mk;
                const float fm = (float)mk;
                const float4 f0 = *(const float4*)(ce_sc + (b * L_CE + l) * CE_SC);
                const float4 f1 = *(const float4*)(ce_sc + (b * L_CE + l) * CE_SC + 4);
                acc[0] = fmaf(fm, f0.x, acc[0]); acc[1] = fmaf(fm, f0.y, acc[1]);
                acc[2] = fmaf(fm, f0.z, acc[2]); acc[3] = fmaf(fm, f0.w, acc[3]);
                acc[4] = fmaf(fm, f1.x, acc[4]); acc[5] = fmaf(fm, f1.y, acc[5]);
                acc[6] = fmaf(fm, f1.z, acc[6]); acc[7] = fmaf(fm, f1.w, acc[7]);
            }
            const float inv = 1.0f / (float)(c > 1 ? c : 1);
#pragma unroll
            for (int q = 0; q < 8; ++q) dst[448 + q] = acc[q] * inv;
        } else if (un < 65) {               // skill_pool
            const int d0 = (un - 57) * 8;
            float acc[8] = {0,0,0,0,0,0,0,0}; int c = 0;
#pragma unroll
            for (int l = 0; l < L_SK; ++l) {
                const int mk = skill_mask[b * L_SK + l]; c += mk;
                const float fm = (float)mk;
                const short8 e = *(const short8*)(skill16 + skill_ids[b * L_SK + l] * 64 + d0);
#pragma unroll
                for (int q = 0; q < 8; ++q) acc[q] = fmaf(fm, bs2f(e[q]), acc[q]);
            }
            const float inv = 1.0f / (float)(c > 1 ? c : 1);
#pragma unroll
            for (int q = 0; q < 8; ++q) dst[456 + d0 + q] = acc[q] * inv;
        } else if (un < 73) {               // vs_pool emb part (msite fp32)
            const int d0 = (un - 65) * 8;
            float acc[8] = {0,0,0,0,0,0,0,0}; int c = 0;
#pragma unroll
            for (int l = 0; l < L_VS; ++l) {
                const int mk = vs_mask[b * L_VS + l]; c += mk;
                const float fm = (float)mk;
                const float4 f0 = *(const float4*)(msite_emb + vs_ids[b * L_VS + l] * DD + d0);
                const float4 f1 = *(const float4*)(msite_emb + vs_ids[b * L_VS + l] * DD + d0 + 4);
                acc[0] = fmaf(fm, f0.x, acc[0]); acc[1] = fmaf(fm, f0.y, acc[1]);
                acc[2] = fmaf(fm, f0.z, acc[2]); acc[3] = fmaf(fm, f0.w, acc[3]);
                acc[4] = fmaf(fm, f1.x, acc[4]); acc[5] = fmaf(fm, f1.y, acc[5]);
                acc[6] = fmaf(fm, f1.z, acc[6]); acc[7] = fmaf(fm, f1.w, acc[7]);
            }
            const float inv = 1.0f / (float)(c > 1 ? c : 1);
#pragma unroll
            for (int q = 0; q < 8; ++q) dst[520 + d0 + q] = acc[q] * inv;
        } else if (un == 73) {              // vs_pool scalar part (6)
            float acc[6] = {0,0,0,0,0,0}; int c = 0;
#pragma unroll
            for (int l = 0; l < L_VS; ++l) {
                const int mk = vs_mask[b * L_VS + l]; c += mk;
                const float fm = (float)mk;
                const float* p = vs_sc + (b * L_VS + l) * SITE_SC;
#pragma unroll
                for (int q = 0; q < 6; ++q) acc[q] = fmaf(fm, p[q], acc[q]);
            }
            const float inv = 1.0f / (float)(c > 1 ? c : 1);
#pragma unroll
            for (int q = 0; q < 6; ++q) dst[584 + q] = acc[q] * inv;
        } else if (un < 82) {               // me_pool emb part (store at 590+d)
            const int d0 = (un - 74) * 8;
            float acc[8] = {0,0,0,0,0,0,0,0}; int c = 0;
#pragma unroll
            for (int l = 0; l < L_ME; ++l) {
                const int mk = me_mask[b * L_ME + l]; c += mk;
                const float fm = (float)mk;
                const short8 e = *(const short8*)(enemy16 + me_ids[b * L_ME + l] * 64 + d0);
#pragma unroll
                for (int q = 0; q < 8; ++q) acc[q] = fmaf(fm, bs2f(e[q]), acc[q]);
            }
            const float inv = 1.0f / (float)(c > 1 ? c : 1);
#pragma unroll
            for (int q = 0; q < 8; ++q) dst[590 + d0 + q] = acc[q] * inv;
        } else if (un == 82) {              // me_pool scalar part (8)
            float acc[8] = {0,0,0,0,0,0,0,0}; int c = 0;
#pragma unroll
            for (int l = 0; l < L_ME; ++l) {
                const int mk = me_mask[b * L_ME + l]; c += mk;
                const float fm = (float)mk;
                const float4 f0 = *(const float4*)(me_sc + (b * L_ME + l) * ME_SC);
                const float4 f1 = *(const float4*)(me_sc + (b * L_ME + l) * ME_SC + 4);
                acc[0] = fmaf(fm, f0.x, acc[0]); acc[1] = fmaf(fm, f0.y, acc[1]);
                acc[2] = fmaf(fm, f0.z, acc[2]); acc[3] = fmaf(fm, f0.w, acc[3]);
                acc[4] = fmaf(fm, f1.x, acc[4]); acc[5] = fmaf(fm, f1.y, acc[5]);
                acc[6] = fmaf(fm, f1.z, acc[6]); acc[7] = fmaf(fm, f1.w, acc[7]);
            }
            const float inv = 1.0f / (float)(c > 1 ? c : 1);
#pragma unroll
            for (int q = 0; q < 8; ++q) dst[654 + q] = acc[q] * inv;
        } else {                            // zero pad 662..671
#pragma unroll
            for (int q = 0; q < 10; ++q) dst[662 + q] = 0.f;
        }
    }
    __syncthreads();

    const short8* Ws8  = (const short8*)WsP;
    const short8* W1a8 = (const short8*)W1aP;
    const f32x4 zero = {0.f, 0.f, 0.f, 0.f};
    const int m15 = lane & 15;
    const int g = lane >> 4;
    const float* arow = s_in + (m15 & (SROWS - 1)) * SSTRIDE;

    // ---- GEMM1: state_input @ W_s over K=672 ----
    f32x4 acc1[4];
#pragma unroll
    for (int nt = 0; nt < 4; ++nt) acc1[nt] = zero;

    for (int kt = 0; kt < 21; ++kt) {
        const int k0 = kt * 32 + 8 * g;
        const float4 v0 = *(const float4*)(arow + k0);
        const float4 v1 = *(const float4*)(arow + k0 + 4);
        short8 a;
        a[0] = f2bs(v0.x); a[1] = f2bs(v0.y); a[2] = f2bs(v0.z); a[3] = f2bs(v0.w);
        a[4] = f2bs(v1.x); a[5] = f2bs(v1.y); a[6] = f2bs(v1.z); a[7] = f2bs(v1.w);
        short8 bfr[4];
#pragma unroll
        for (int nt = 0; nt < 4; ++nt) bfr[nt] = Ws8[(kt * 16 + w * 4 + nt) * 64 + lane];
#pragma unroll
        for (int nt = 0; nt < 4; ++nt)
            acc1[nt] = __builtin_amdgcn_mfma_f32_16x16x32_bf16(a, bfr[nt], acc1[nt], 0, 0, 0);
    }

    // ---- epilogue: tanh, value partials, A2 pack ----
    float sr[4][4];
    float pv[4] = {0.f, 0.f, 0.f, 0.f};
#pragma unroll
    for (int nt = 0; nt < 4; ++nt) {
        const int n = w * 64 + nt * 16 + m15;
        const float bsn = b_s[n];
        const float wvn = W_v[n];
#pragma unroll
        for (int r = 0; r < 4; ++r) {
            const float sv = fast_tanh(acc1[nt][r] + bsn);
            sr[nt][r] = sv;
            pv[r] = fmaf(sv, wvn, pv[r]);
        }
    }
#pragma unroll
    for (int r = 0; r < SROWS; ++r) {
        float v = pv[r];
        v += __shfl_xor(v, 1);
        v += __shfl_xor(v, 2);
        v += __shfl_xor(v, 4);
        v += __shfl_xor(v, 8);
        if (lane == 0) red[w][r] = v;
    }
    if (g == 0) {
#pragma unroll
        for (int nt = 0; nt < 4; ++nt) {
            const int n = w * 64 + nt * 16 + m15;
            const int kt2 = n >> 5;
            const int lo16 = (n >> 3) & 3;
#pragma unroll
            for (int r = 0; r < 4; ++r) {
                const int pi = (kt2 * 64 + (r + 16 * lo16)) * 8 + (n & 7);
                sA2[pi] = (ushort)f2bs(sr[nt][r]);
            }
        }
    }
    __syncthreads();

    if (t < SROWS) {
        out_value[b0 + t] = red[0][t] + red[1][t] + red[2][t] + red[3][t] + b_v[0];
    }

    // ---- GEMM2: state_repr @ W1[:256,:] over K=256 -> s_part fp32 ----
    const short8* sA2_8 = (const short8*)sA2;
    f32x4 acc2[4];
#pragma unroll
    for (int nt = 0; nt < 4; ++nt) acc2[nt] = zero;
#pragma unroll
    for (int kt = 0; kt < 8; ++kt) {
        const short8 a2 = sA2_8[kt * 64 + lane];
        short8 bfr[4];
#pragma unroll
        for (int nt = 0; nt < 4; ++nt) bfr[nt] = W1a8[(kt * 16 + w * 4 + nt) * 64 + lane];
#pragma unroll
        for (int nt = 0; nt < 4; ++nt)
            acc2[nt] = __builtin_amdgcn_mfma_f32_16x16x32_bf16(a2, bfr[nt], acc2[nt], 0, 0, 0);
    }
    if (g == 0) {
#pragma unroll
        for (int nt = 0; nt < 4; ++nt) {
            const int n = w * 64 + nt * 16 + m15;
#pragma unroll
            for (int r = 0; r < SROWS; ++r)
                s_part[(b0 + r) * HH + n] = acc2[nt][r];
        }
    }
}

// ---- action A1 TAIL chunk (k0 >= 384): tgt_pool / scalars / pad ----
__device__ __forceinline__ short8 tail_chunk(
    int k0, int m, int b,
    const int* __restrict__ tgt_ids, const int* __restrict__ tgt_mask,
    const ushort* __restrict__ emb16, const float* __restrict__ action_scalars)
{
    short8 val;
    if (k0 < 448) {
        const int d = k0 - 384;
        const ushort* enemy16 = emb16 + RO_ENEMY * 64;
        const int base = (b * NN + m) * L_TGT;
        const int4 t0v = *(const int4*)(tgt_ids + base);
        const int4 t1v = *(const int4*)(tgt_ids + base + 4);
        const int4 m0v = *(const int4*)(tgt_mask + base);
        const int4 m1v = *(const int4*)(tgt_mask + base + 4);
        const int tid[8] = {t0v.x, t0v.y, t0v.z, t0v.w, t1v.x, t1v.y, t1v.z, t1v.w};
        const int tmk[8] = {m0v.x, m0v.y, m0v.z, m0v.w, m1v.x, m1v.y, m1v.z, m1v.w};
        float accq[8] = {0.f, 0.f, 0.f, 0.f, 0.f, 0.f, 0.f, 0.f};
        int c = 0;
#pragma unroll
        for (int l = 0; l < L_TGT; ++l) {
            const int mk = tmk[l];
            c += mk;
            const float fm = (float)mk;
            const short8 e = *(const short8*)(enemy16 + tid[l] * 64 + d);
#pragma unroll
            for (int q = 0; q < 8; ++q) accq[q] = fmaf(fm, bs2f(e[q]), accq[q]);
        }
        const float inv = 1.0f / (float)(c > 1 ? c : 1);
#pragma unroll
        for (int q = 0; q < 8; ++q) val[q] = f2bs(accq[q] * inv);
    } else if (k0 < 464) {
        const float* sc = action_scalars + (b * NN + m) * ACT_SC + (k0 - 448);
        const float4 f0 = *(const float4*)sc;
        const float4 f1 = *(const float4*)(sc + 4);
        val[0] = f2bs(f0.x); val[1] = f2bs(f0.y); val[2] = f2bs(f0.z); val[3] = f2bs(f0.w);
        val[4] = f2bs(f1.x); val[5] = f2bs(f1.y); val[6] = f2bs(f1.z); val[7] = f2bs(f1.w);
    } else {
#pragma unroll
        for (int q = 0; q < 8; ++q) val[q] = 0;
    }
    return val;
}

// ===================== MFMA action kernel (512 threads, 8 waves) =====================
// Single-phase 15-tile A1 staging: all 12 emb-tile DMAs issued at once (waves
// 0..7 take kt=w, waves 0..3 also kt=8+w); tail kt 12..14 built concurrently;
// ONE vmcnt drain; GEMM1 runs kt 0..14 with no mid-loop barriers and a 2-deep
// W-prefetch pipeline flowing into GEMM2. 5 barriers total (was 7).
__global__ __launch_bounds__(512) void action_mfma_kernel(
    const int* __restrict__ action_ids, const float* __restrict__ action_scalars,
    const int* __restrict__ tgt_ids, const int* __restrict__ tgt_mask,
    const ushort* __restrict__ emb16,
    const ushort* __restrict__ WaP, const float* __restrict__ b_a,
    const ushort* __restrict__ W1bP, const float* __restrict__ b1,
    const float* __restrict__ W2, const float* __restrict__ b2,
    const float* __restrict__ s_part, float* __restrict__ out_logits)
{
    __shared__ ushort sA[15 * 2048];       // 61,440 B: 15 MFMA tiles (A2 in 0..7)
    __shared__ float red[8][64];           // 2,048 B
    __shared__ int s_ids[64 * 6];          // 1,536 B  (total 65,024 B)

    const int t = threadIdx.x;
    const int b = blockIdx.x;
    const int w = t >> 6;        // wave 0..7, owns cols w*32 .. w*32+31
    const int lane = t & 63;
    const int m15 = lane & 15;

    const short8* sA8  = (const short8*)sA;
    short8* sA8w = (short8*)sA;
    const short8* Wa8  = (const short8*)WaP;
    const short8* W1b8 = (const short8*)W1bP;
    const f32x4 zero = {0.f, 0.f, 0.f, 0.f};

    // 2-deep W prefetch pipeline: bp[parity][nt]
    short8 bp00 = Wa8[(0 * 16 + w * 2 + 0) * 64 + lane];
    short8 bp01 = Wa8[(0 * 16 + w * 2 + 1) * 64 + lane];
    short8 bp10 = Wa8[(1 * 16 + w * 2 + 0) * 64 + lane];
    short8 bp11 = Wa8[(1 * 16 + w * 2 + 1) * 64 + lane];

    // ---- stage action ids (coalesced) ----
    for (int i = t; i < 64 * 6; i += 512) s_ids[i] = action_ids[b * (64 * 6) + i];
    __syncthreads();   // B1

    const int ROFFS[6] = {RO_AT, RO_SRC, RO_CARD, RO_UNIT, RO_ENEMY, RO_SKILL};

    // ---- single-phase DMA: stage ALL emb tiles kt 0..11 ----
    {
        const int kt = w;                          // waves 0..7 -> tiles 0..7
        const int j = kt >> 1;
        const int koff = (kt & 1) * 32 + (lane >> 4) * 8;
#pragma unroll
        for (int i = 0; i < 4; ++i) {
            const int id = s_ids[(i * 16 + m15) * 6 + j];
            async_copy16(emb16 + (ROFFS[j] + id) * 64 + koff, sA + kt * 2048 + i * 512);
        }
    }
    if (w < 4) {
        const int kt = 8 + w;                      // waves 0..3 -> tiles 8..11
        const int j = kt >> 1;
        const int koff = (kt & 1) * 32 + (lane >> 4) * 8;
#pragma unroll
        for (int i = 0; i < 4; ++i) {
            const int id = s_ids[(i * 16 + m15) * 6 + j];
            async_copy16(emb16 + (ROFFS[j] + id) * 64 + koff, sA + kt * 2048 + i * 512);
        }
    }

    // ---- tail build (kt 12..14 -> tiles 12..14) while DMA is in flight ----
    {
        const int m = lane;
        const int mt_b = m >> 4, mrow = m & 15;
        for (int kc = 48 + w; kc < 60; kc += 8) {
            const int k0 = kc << 3;
            const short8 val = tail_chunk(k0, m, b, tgt_ids, tgt_mask, emb16, action_scalars);
            const int ktl = k0 >> 5;               // tiles 12..14
            const int lo = kc & 3;
            sA8w[(ktl * 4 + mt_b) * 64 + mrow + 16 * lo] = val;
        }
    }
    __syncthreads();   // B2: the ONLY DMA drain; full A1 resident

    // epilogue-1 bias, loaded early
    float ba[2];
#pragma unroll
    for (int nt = 0; nt < 2; ++nt) ba[nt] = b_a[w * 32 + nt * 16 + m15];

    f32x4 acc[4][2];
#pragma unroll
    for (int i = 0; i < 4; ++i) { acc[i][0] = zero; acc[i][1] = zero; }

    // ---- GEMM1: kt 0..14, no barriers, 2-deep W prefetch ----
#pragma unroll
    for (int kt = 0; kt < 15; ++kt) {
        short8 b0, b1;
        if ((kt & 1) == 0) { b0 = bp00; b1 = bp01; }
        else               { b0 = bp10; b1 = bp11; }
        // prefetch kt+2 (GEMM1), or GEMM2 kt0/kt1 at the tail
        if (kt + 2 < 15) {
            if ((kt & 1) == 0) {
                bp00 = Wa8[((kt + 2) * 16 + w * 2 + 0) * 64 + lane];
                bp01 = Wa8[((kt + 2) * 16 + w * 2 + 1) * 64 + lane];
            } else {
                bp10 = Wa8[((kt + 2) * 16 + w * 2 + 0) * 64 + lane];
                bp11 = Wa8[((kt + 2) * 16 + w * 2 + 1) * 64 + lane];
            }
        } else if (kt + 2 == 15) {   // kt==13 (odd): prefetch GEMM2 kt0 into bp10/11? parity 1
            bp10 = W1b8[(0 * 16 + w * 2 + 0) * 64 + lane];
            bp11 = W1b8[(0 * 16 + w * 2 + 1) * 64 + lane];
        } else {                     // kt==14 (even): prefetch GEMM2 kt1 into parity 0
            bp00 = W1b8[(1 * 16 + w * 2 + 0) * 64 + lane];
            bp01 = W1b8[(1 * 16 + w * 2 + 1) * 64 + lane];
        }
        short8 a[4];
#pragma unroll
        for (int mti = 0; mti < 4; ++mti) a[mti] = sA8[(kt * 4 + mti) * 64 + lane];
        __builtin_amdgcn_s_setprio(1);
#pragma unroll
        for (int mti = 0; mti < 4; ++mti) {
            acc[mti][0] = __builtin_amdgcn_mfma_f32_16x16x32_bf16(a[mti], b0, acc[mti][0], 0, 0, 0);
            acc[mti][1] = __builtin_amdgcn_mfma_f32_16x16x32_bf16(a[mti], b1, acc[mti][1], 0, 0, 0);
        }
        __builtin_amdgcn_s_setprio(0);
    }
    __syncthreads();   // B5: all A1 reads done before writing A2

    // ---- epilogue 1: action_repr = tanh(acc + b_a) -> packed A2 in tiles 0..7 ----
#pragma unroll
    for (int mti = 0; mti < 4; ++mti)
#pragma unroll
        for (int nt = 0; nt < 2; ++nt) {
            const int n = w * 32 + nt * 16 + m15;       // GEMM2 k-dim
            const int kt2 = n >> 5;
            const int lo16 = (n >> 3) & 3;
#pragma unroll
            for (int r = 0; r < 4; ++r) {
                const int mm = mti * 16 + (lane >> 4) * 4 + r;
                const float h = fast_tanh(acc[mti][nt][r] + ba[nt]);
                const int pi = ((kt2 * 4 + mti) * 64 + ((mm & 15) + 16 * lo16)) * 8 + (n & 7);
                sA[pi] = (ushort)f2bs(h);
            }
        }
    __syncthreads();   // B6: A2 ready

    // epilogue-2 constants, loaded early (latency hides under GEMM2)
    float sp[2], w2v[2];
#pragma unroll
    for (int nt = 0; nt < 2; ++nt) {
        const int n = w * 32 + nt * 16 + m15;
        sp[nt]  = s_part[b * HH + n] + b1[n];
        w2v[nt] = W2[n];
    }

    // ---- GEMM2: kt 0..7, 2-deep prefetch continues (kt0 in parity1, kt1 in parity0) ----
#pragma unroll
    for (int i = 0; i < 4; ++i) { acc[i][0] = zero; acc[i][1] = zero; }

#pragma unroll
    for (int kt = 0; kt < 8; ++kt) {
        short8 b0, b1;
        if ((kt & 1) == 0) { b0 = bp10; b1 = bp11; }   // GEMM2 even kt in parity1
        else               { b0 = bp00; b1 = bp01; }
        if (kt + 2 < 8) {
            if ((kt & 1) == 0) {
                bp10 = W1b8[((kt + 2) * 16 + w * 2 + 0) * 64 + lane];
                bp11 = W1b8[((kt + 2) * 16 + w * 2 + 1) * 64 + lane];
            } else {
                bp00 = W1b8[((kt + 2) * 16 + w * 2 + 0) * 64 + lane];
                bp01 = W1b8[((kt + 2) * 16 + w * 2 + 1) * 64 + lane];
            }
        }
        short8 a[4];
#pragma unroll
        for (int mti = 0; mti < 4; ++mti) a[mti] = sA8[(kt * 4 + mti) * 64 + lane];
        __builtin_amdgcn_s_setprio(1);
#pragma unroll
        for (int mti = 0; mti < 4; ++mti) {
            acc[mti][0] = __builtin_amdgcn_mfma_f32_16x16x32_bf16(a[mti], b0, acc[mti][0], 0, 0, 0);
            acc[mti][1] = __builtin_amdgcn_mfma_f32_16x16x32_bf16(a[mti], b1, acc[mti][1], 0, 0, 0);
        }
        __builtin_amdgcn_s_setprio(0);
    }

    // ---- epilogue 2: logits[m] = sum_n tanh(acc + s_part + b1) * W2[n] + b2 ----
    float part[4][4];
#pragma unroll
    for (int mti = 0; mti < 4; ++mti)
#pragma unroll
        for (int r = 0; r < 4; ++r) part[mti][r] = 0.f;

#pragma unroll
    for (int mti = 0; mti < 4; ++mti)
#pragma unroll
        for (int nt = 0; nt < 2; ++nt)
#pragma unroll
            for (int r = 0; r < 4; ++r)
                part[mti][r] += fast_tanh(acc[mti][nt][r] + sp[nt]) * w2v[nt];

    // DPP row-sum over the 16 col-lanes; lane m15==15 holds it
#pragma unroll
    for (int mti = 0; mti < 4; ++mti)
#pragma unroll
        for (int r = 0; r < 4; ++r)
            part[mti][r] = sum16_dpp(part[mti][r]);

    if (m15 == 15) {
#pragma unroll
        for (int mti = 0; mti < 4; ++mti)
#pragma unroll
            for (int r = 0; r < 4; ++r) {
                const int mm = mti * 16 + (lane >> 4) * 4 + r;
                red[w][mm] = part[mti][r];
            }
    }
    __syncthreads();   // B7
    if (t < 64) {
        float s = b2[0];
#pragma unroll
        for (int wi = 0; wi < 8; ++wi) s += red[wi][t];
        out_logits[b * NN + t] = s;
    }
}

extern "C" void kernel_launch(void* const* d_in, const int* in_sizes, int n_in,
                              void* d_out, int out_size, void* d_ws, size_t ws_size,
                              hipStream_t stream) {
    const float* state_scalars = (const float*)d_in[0];
    const int*   mode_id       = (const int*)d_in[1];
    const int*   terrain_id    = (const int*)d_in[2];
    const int*   site_type_id  = (const int*)d_in[3];
    const int*   hand_ids      = (const int*)d_in[4];
    const int*   hand_mask     = (const int*)d_in[5];
    const int*   unit_ids      = (const int*)d_in[6];
    const int*   unit_mask     = (const int*)d_in[7];
    const int*   ce_ids        = (const int*)d_in[8];
    const float* ce_sc         = (const float*)d_in[9];
    const int*   ce_mask       = (const int*)d_in[10];
    const int*   skill_ids     = (const int*)d_in[11];
    const int*   skill_mask    = (const int*)d_in[12];
    const int*   vs_ids        = (const int*)d_in[13];
    const float* vs_sc         = (const float*)d_in[14];
    const int*   vs_mask       = (const int*)d_in[15];
    const int*   me_ids        = (const int*)d_in[16];
    const float* me_sc         = (const float*)d_in[17];
    const int*   me_mask       = (const int*)d_in[18];
    const int*   action_ids    = (const int*)d_in[19];
    const float* action_scalars= (const float*)d_in[20];
    const int*   tgt_ids       = (const int*)d_in[21];
    const int*   tgt_mask      = (const int*)d_in[22];
    const float* card_emb      = (const float*)d_in[23];
    const float* unit_emb      = (const float*)d_in[24];
    const float* enemy_emb     = (const float*)d_in[25];
    const float* at_emb        = (const float*)d_in[26];
    const float* src_emb       = (const float*)d_in[27];
    const float* mode_emb      = (const float*)d_in[28];
    const float* ter_emb       = (const float*)d_in[29];
    const float* site_emb      = (const float*)d_in[30];
    const float* skill_emb     = (const float*)d_in[31];
    const float* msite_emb     = (const float*)d_in[32];
    const float* W_s           = (const float*)d_in[33];
    const float* b_s           = (const float*)d_in[34];
    const float* W_a           = (const float*)d_in[35];
    const float* b_a           = (const float*)d_in[36];
    const float* W1            = (const float*)d_in[37];
    const float* b1            = (const float*)d_in[38];
    const float* W2            = (const float*)d_in[39];
    const float* b2            = (const float*)d_in[40];
    const float* W_v           = (const float*)d_in[41];
    const float* b_v           = (const float*)d_in[42];

    float* out_logits = (float*)d_out;                   // [B, N]
    float* out_value  = (float*)d_out + (size_t)BB * NN; // [B]

    // workspace layout (16B-aligned sections)
    char* ws = (char*)d_ws;
    float*  s_part = (float*)ws;                          // 2,097,152 B
    ushort* WaP    = (ushort*)(ws + 2097152);             // 245,760 B
    ushort* W1bP   = (ushort*)(ws + 2342912);             // 131,072 B
    ushort* emb16  = (ushort*)(ws + 2473984);             //  97,280 B
    ushort* WsP    = (ushort*)(ws + 2571264);             // 344,064 B
    ushort* W1aP   = (ushort*)(ws + 2915328);             // 131,072 B (end 3,046,400)

    pack_kernel<<<(T4 + 255) / 256, 256, 0, stream>>>(
        W_a, W1, W_s, at_emb, src_emb, card_emb, unit_emb, enemy_emb, skill_emb,
        WaP, W1bP, emb16, WsP, W1aP);

    state_mfma_kernel<<<BB / SROWS, 256, 0, stream>>>(
        state_scalars, mode_id, terrain_id, site_type_id,
        hand_ids, hand_mask, unit_ids, unit_mask,
        ce_ids, ce_sc, ce_mask, skill_ids, skill_mask,
        vs_ids, vs_sc, vs_mask, me_ids, me_sc, me_mask,
        mode_emb, ter_emb, site_emb, msite_emb, emb16,
        WsP, b_s, W1aP, W_v, b_v, s_part, out_value);

    action_mfma_kernel<<<BB, 512, 0, stream>>>(
        action_ids, action_scalars, tgt_ids, tgt_mask,
        emb16, WaP, b_a, W1bP, b1, W2, b2, s_part, out_logits);
}